// Round 1
// baseline (338.648 us; speedup 1.0000x reference)
//
#include <hip/hip_runtime.h>

#define B_   8
#define C_   256
#define W_   8192
#define F_   256
#define KK   3
#define KC   768            // KK * C_
#define COEF 0.03608439182435161f   // 1/sqrt(3*256)
#define AST  40             // LDS row stride (elements): 32 payload + 8 pad; 80B = 16B-aligned, 20-bank stride

using f32x4  = __attribute__((ext_vector_type(4))) float;
using bf16x8 = __attribute__((ext_vector_type(8))) __bf16;

__device__ __forceinline__ unsigned short f2bf(float x) {
    union { float f; unsigned int u; } v; v.f = x;
    unsigned int u = v.u;
    u += 0x7FFFu + ((u >> 16) & 1u);   // RNE
    return (unsigned short)(u >> 16);
}

// kernelT[f][k*256+c] = bf16(kernel[k][c][f] * COEF)  -- A-operand, reduce-dim contiguous
__global__ void prep_kt(const float* __restrict__ kern, unsigned short* __restrict__ kT) {
    int idx = blockIdx.x * 256 + threadIdx.x;   // ((k*256)+c)*256 + f, 196608 total
    int f  = idx & 255;
    int kc = idx >> 8;
    kT[f * KC + kc] = f2bf(kern[idx] * COEF);
}

// denom[b][f] = rsqrt( sum_{k,c} (kernel[k,c,f]*COEF*(style[b,c]+1))^2 )
__global__ void prep_denom(const float* __restrict__ kern, const float* __restrict__ style,
                           float* __restrict__ denom) {
    __shared__ float red[256];
    int bf = blockIdx.x;            // b*256 + f
    int b = bf >> 8, f = bf & 255;
    int c = threadIdx.x;
    float s = (style[b * C_ + c] + 1.0f) * COEF;
    float sum = 0.f;
#pragma unroll
    for (int k = 0; k < KK; ++k) {
        float w = kern[(k * C_ + c) * F_ + f] * s;
        sum += w * w;
    }
    red[c] = sum;
    __syncthreads();
    for (int s2 = 128; s2 > 0; s2 >>= 1) {
        if (c < s2) red[c] += red[c + s2];
        __syncthreads();
    }
    if (c == 0) denom[bf] = rsqrtf(red[0]);
}

// Main: per (b, 128-f-tile, 128-w-tile) block; 4 waves, each 64x64 via 4x4 of 16x16x32 MFMA.
__global__ __launch_bounds__(256) void conv_mod(
        const float* __restrict__ feat, const float* __restrict__ style,
        const unsigned short* __restrict__ kT, const float* __restrict__ denom,
        float* __restrict__ out) {
    __shared__ unsigned short As[128 * AST];  // [fcol][k]  (A fragments: k contiguous)
    __shared__ unsigned short Bs[128 * AST];  // [n][k]     (B fragments: k contiguous)
    __shared__ float smod[C_];

    const int tid  = threadIdx.x;
    const int b    = blockIdx.z;
    const int f0   = blockIdx.y * 128;
    const int w0   = blockIdx.x * 128;
    const int lane = tid & 63, wave = tid >> 6;
    const int wm   = (wave >> 1) * 64;   // wave f-offset in tile
    const int wn   = (wave & 1) * 64;    // wave w-offset in tile
    const int lm   = lane & 15, lq = lane >> 4;

    if (tid < C_) smod[tid] = style[b * C_ + tid] + 1.0f;

    const float* featb = feat + (size_t)b * C_ * W_;

    f32x4 acc[4][4] = {};

    const int afcol = tid >> 1, ahalf = tid & 1;  // A staging: 2 threads per f-row
    const int bcol = tid & 31, brbase = tid >> 5; // B staging: 32 threads sweep w, 8 rows

    for (int kc0 = 0; kc0 < KC; kc0 += 32) {
        const int k     = kc0 >> 8;      // tap index (k outer, c inner)
        const int c0    = kc0 & 255;
        const int shift = k - 1;
        __syncthreads();  // prev iter frag reads done (also covers smod init)

        // ---- A tile: kernelT[f0+fcol][kc0 .. +32) -> As[fcol][0..32) ----
        {
            const uint4* src = (const uint4*)(kT + (size_t)(f0 + afcol) * KC + kc0 + ahalf * 16);
            uint4 d0 = src[0];
            uint4 d1 = src[1];
            uint4* dst = (uint4*)(&As[afcol * AST + ahalf * 16]);
            dst[0] = d0; dst[1] = d1;
        }

        // ---- B tile: Bs[n][r] = bf16(feat[b][c0+r][w0+n+shift] * smod[c0+r]) ----
#pragma unroll
        for (int j = 0; j < 4; ++j) {
            const int r = brbase + j * 8;
            const float sm = smod[c0 + r];
            const float* frow = featb + (size_t)(c0 + r) * W_;
#pragma unroll
            for (int i = 0; i < 4; ++i) {
                const int n = bcol + i * 32;
                const int wpos = w0 + n + shift;
                float v = ((unsigned)wpos < (unsigned)W_) ? frow[wpos] : 0.0f;
                Bs[n * AST + r] = f2bf(v * sm);
            }
        }
        __syncthreads();

        // ---- fragments + MFMA ----
        bf16x8 a_frag[4], b_frag[4];
#pragma unroll
        for (int mi = 0; mi < 4; ++mi)
            a_frag[mi] = *(const bf16x8*)&As[(wm + mi * 16 + lm) * AST + lq * 8];
#pragma unroll
        for (int ni = 0; ni < 4; ++ni)
            b_frag[ni] = *(const bf16x8*)&Bs[(wn + ni * 16 + lm) * AST + lq * 8];
#pragma unroll
        for (int mi = 0; mi < 4; ++mi)
#pragma unroll
            for (int ni = 0; ni < 4; ++ni)
                acc[mi][ni] = __builtin_amdgcn_mfma_f32_16x16x32_bf16(
                    a_frag[mi], b_frag[ni], acc[mi][ni], 0, 0, 0);
    }

    // ---- epilogue: out[b][f][w] = acc * denom[b][f] ----
    // C/D layout: col(w) = lane&15, row(f) = (lane>>4)*4 + reg   [measured m89/m91]
    const int bofs = b * F_;
#pragma unroll
    for (int mi = 0; mi < 4; ++mi) {
        const int fbase = f0 + wm + mi * 16 + lq * 4;
        const float d0 = denom[bofs + fbase + 0];
        const float d1 = denom[bofs + fbase + 1];
        const float d2 = denom[bofs + fbase + 2];
        const float d3 = denom[bofs + fbase + 3];
#pragma unroll
        for (int ni = 0; ni < 4; ++ni) {
            const int wcol = w0 + wn + ni * 16 + lm;
            float* op = out + ((size_t)(bofs + fbase)) * W_ + wcol;
            f32x4 a = acc[mi][ni];
            op[0]                  = a.x * d0;
            op[(size_t)W_]         = a.y * d1;
            op[2 * (size_t)W_]     = a.z * d2;
            op[3 * (size_t)W_]     = a.w * d3;
        }
    }
}

extern "C" void kernel_launch(void* const* d_in, const int* in_sizes, int n_in,
                              void* d_out, int out_size, void* d_ws, size_t ws_size,
                              hipStream_t stream) {
    const float* feature = (const float*)d_in[0];   // [8,256,8192]
    const float* style   = (const float*)d_in[1];   // [8,256]
    const float* kern    = (const float*)d_in[2];   // [3,256,256]
    float* out = (float*)d_out;                     // [8,256,8192]

    unsigned short* kT = (unsigned short*)d_ws;                   // 256*768 bf16 = 384 KiB
    float* denom = (float*)((char*)d_ws + (size_t)F_ * KC * 2);   // 2048 fp32

    hipLaunchKernelGGL(prep_kt,    dim3(KC), dim3(256), 0, stream, kern, kT);
    hipLaunchKernelGGL(prep_denom, dim3(B_ * F_), dim3(256), 0, stream, kern, style, denom);
    hipLaunchKernelGGL(conv_mod,   dim3(W_ / 128, F_ / 128, B_), dim3(256), 0, stream,
                       feature, style, kT, denom, out);
}

// Round 2
// 213.811 us; speedup vs baseline: 1.5839x; 1.5839x over previous
//
#include <hip/hip_runtime.h>

#define B_   8
#define C_   256
#define W_   8192
#define F_   256
#define KK   3
#define KC   768            // KK * C_
#define WP   (W_ + 2)       // padded rows in featT (zero row at w=-1 and w=W)
#define COEF 0.03608439182435161f   // 1/sqrt(3*256)

using f32x4  = __attribute__((ext_vector_type(4))) float;
using bf16x8 = __attribute__((ext_vector_type(8))) __bf16;

__device__ __forceinline__ unsigned short f2bf(float x) {
    union { float f; unsigned int u; } v; v.f = x;
    unsigned int u = v.u;
    u += 0x7FFFu + ((u >> 16) & 1u);   // RNE
    return (unsigned short)(u >> 16);
}

// kernelT[f][k*256+c] = bf16(kernel[k][c][f] * COEF)  -- A-operand, reduce-dim contiguous
__global__ void prep_kt(const float* __restrict__ kern, unsigned short* __restrict__ kT) {
    int idx = blockIdx.x * 256 + threadIdx.x;   // ((k*256)+c)*256 + f
    int f  = idx & 255;
    int kc = idx >> 8;
    kT[f * KC + kc] = f2bf(kern[idx] * COEF);
}

// denom[b][f] = rsqrt( sum_{k,c} (kernel[k,c,f]*COEF*(style[b,c]+1))^2 )
__global__ void prep_denom(const float* __restrict__ kern, const float* __restrict__ style,
                           float* __restrict__ denom) {
    __shared__ float red[256];
    int bf = blockIdx.x;            // b*256 + f
    int b = bf >> 8, f = bf & 255;
    int c = threadIdx.x;
    float s = (style[b * C_ + c] + 1.0f) * COEF;
    float sum = 0.f;
#pragma unroll
    for (int k = 0; k < KK; ++k) {
        float w = kern[(k * C_ + c) * F_ + f] * s;
        sum += w * w;
    }
    red[c] = sum;
    __syncthreads();
    for (int s2 = 128; s2 > 0; s2 >>= 1) {
        if (c < s2) red[c] += red[c + s2];
        __syncthreads();
    }
    if (c == 0) denom[bf] = rsqrtf(red[0]);
}

// featT[b][w+1][c] = bf16( feat[b][c][w] * (style[b][c]+1) )  via 64x64 LDS transpose
__global__ __launch_bounds__(256) void prep_featT(const float* __restrict__ feat,
                                                  const float* __restrict__ style,
                                                  unsigned short* __restrict__ featT) {
    __shared__ float tile[64][65];
    const int tid = threadIdx.x;
    const int b = blockIdx.z, c0 = blockIdx.y * 64, w0 = blockIdx.x * 64;
    const int tx = tid & 63, ty = tid >> 6;          // ty 0..3

    const float* src = feat + ((size_t)b * C_ + c0) * W_ + w0;
#pragma unroll
    for (int i = 0; i < 16; ++i) {
        int cl = ty * 16 + i;
        tile[cl][tx] = src[(size_t)cl * W_ + tx];    // 64 consecutive floats per wave row
    }
    __syncthreads();

    const int cp = tid & 31, wb = tid >> 5;          // cp: c-pair 0..31, wb: w row 0..7
    const float s0 = style[b * C_ + c0 + 2 * cp]     + 1.0f;
    const float s1 = style[b * C_ + c0 + 2 * cp + 1] + 1.0f;
#pragma unroll
    for (int i = 0; i < 8; ++i) {
        int wl = wb + i * 8;
        float v0 = tile[2 * cp][wl] * s0;
        float v1 = tile[2 * cp + 1][wl] * s1;
        unsigned int pk = (unsigned int)f2bf(v0) | ((unsigned int)f2bf(v1) << 16);
        unsigned int* dst = (unsigned int*)(featT + ((size_t)b * WP + (w0 + wl + 1)) * C_ + c0);
        dst[cp] = pk;                                // 128 B contiguous per half-wave
    }
}

// zero the two pad rows (w=-1, w=W) per batch: 8*2*256 = 4096 elements
__global__ void zero_pad(unsigned short* __restrict__ featT) {
    int idx = blockIdx.x * 256 + threadIdx.x;        // 0..4095
    int b = idx >> 9, r = (idx >> 8) & 1, c = idx & 255;
    size_t row = r ? (size_t)(WP - 1) : 0;
    featT[((size_t)b * WP + row) * C_ + c] = 0;
}

// Main: no LDS, no barriers. Per (b, 128f, 128w) block; 4 waves x (4x4) 16x16x32 MFMA.
// Fragments load direct from global; offset for iteration t is ptr + 32*t for BOTH
// operands (featT row stride 256 == per-tap kc span, so tap shift = +1 row = +256).
__global__ __launch_bounds__(256) void conv_mod(
        const unsigned short* __restrict__ featT,
        const unsigned short* __restrict__ kT,
        const float* __restrict__ denom,
        float* __restrict__ out) {
    const int tid  = threadIdx.x;
    const int b    = blockIdx.z;
    const int f0   = blockIdx.y * 128;
    const int w0   = blockIdx.x * 128;
    const int lane = tid & 63, wave = tid >> 6;
    const int wm   = (wave >> 1) * 64;   // wave f-offset in tile
    const int wn   = (wave & 1) * 64;    // wave w-offset in tile
    const int lm   = lane & 15, lq = lane >> 4;

    const unsigned short* ap[4];
    const unsigned short* bp[4];
#pragma unroll
    for (int mi = 0; mi < 4; ++mi)
        ap[mi] = kT + (size_t)(f0 + wm + mi * 16 + lm) * KC + lq * 8;
#pragma unroll
    for (int ni = 0; ni < 4; ++ni)
        bp[ni] = featT + ((size_t)b * WP + (w0 + wn + ni * 16 + lm)) * C_ + lq * 8;

    f32x4 acc[4][4] = {};
    bf16x8 aC[4], bC[4], aN[4], bN[4];

#pragma unroll
    for (int i = 0; i < 4; ++i) {
        aC[i] = *(const bf16x8*)(ap[i]);
        bC[i] = *(const bf16x8*)(bp[i]);
    }

#pragma unroll
    for (int t = 0; t < 24; ++t) {
        const int noff = (t < 23) ? (t + 1) * 32 : 0;   // last prefetch redundant, harmless
#pragma unroll
        for (int i = 0; i < 4; ++i) {
            aN[i] = *(const bf16x8*)(ap[i] + noff);
            bN[i] = *(const bf16x8*)(bp[i] + noff);
        }
#pragma unroll
        for (int mi = 0; mi < 4; ++mi)
#pragma unroll
            for (int ni = 0; ni < 4; ++ni)
                acc[mi][ni] = __builtin_amdgcn_mfma_f32_16x16x32_bf16(
                    aC[mi], bC[ni], acc[mi][ni], 0, 0, 0);
#pragma unroll
        for (int i = 0; i < 4; ++i) { aC[i] = aN[i]; bC[i] = bN[i]; }
    }

    // epilogue: out[b][f][w] = acc * denom[b][f]
    // C/D layout: col(w) = lane&15, row(f) = (lane>>4)*4 + reg   [measured m89/m91]
    const int bofs = b * F_;
#pragma unroll
    for (int mi = 0; mi < 4; ++mi) {
        const int fbase = f0 + wm + mi * 16 + lq * 4;
        const float d0 = denom[bofs + fbase + 0];
        const float d1 = denom[bofs + fbase + 1];
        const float d2 = denom[bofs + fbase + 2];
        const float d3 = denom[bofs + fbase + 3];
#pragma unroll
        for (int ni = 0; ni < 4; ++ni) {
            const int wcol = w0 + wn + ni * 16 + lm;
            float* op = out + ((size_t)(bofs + fbase)) * W_ + wcol;
            f32x4 a = acc[mi][ni];
            op[0]              = a.x * d0;
            op[(size_t)W_]     = a.y * d1;
            op[2 * (size_t)W_] = a.z * d2;
            op[3 * (size_t)W_] = a.w * d3;
        }
    }
}

extern "C" void kernel_launch(void* const* d_in, const int* in_sizes, int n_in,
                              void* d_out, int out_size, void* d_ws, size_t ws_size,
                              hipStream_t stream) {
    const float* feature = (const float*)d_in[0];   // [8,256,8192]
    const float* style   = (const float*)d_in[1];   // [8,256]
    const float* kern    = (const float*)d_in[2];   // [3,256,256]
    float* out = (float*)d_out;                     // [8,256,8192]

    // ws layout: kT (384 KiB) | denom (8 KiB) | featT (8*8194*256 bf16 = 32.0 MiB)
    unsigned short* kT    = (unsigned short*)d_ws;
    float*          denom = (float*)((char*)d_ws + (size_t)F_ * KC * 2);
    unsigned short* featT = (unsigned short*)((char*)d_ws + (size_t)F_ * KC * 2 + 8192);

    hipLaunchKernelGGL(prep_kt,    dim3(KC),          dim3(256), 0, stream, kern, kT);
    hipLaunchKernelGGL(prep_denom, dim3(B_ * F_),     dim3(256), 0, stream, kern, style, denom);
    hipLaunchKernelGGL(zero_pad,   dim3(16),          dim3(256), 0, stream, featT);
    hipLaunchKernelGGL(prep_featT, dim3(W_ / 64, C_ / 64, B_), dim3(256), 0, stream,
                       feature, style, featT);
    hipLaunchKernelGGL(conv_mod,   dim3(W_ / 128, F_ / 128, B_), dim3(256), 0, stream,
                       featT, kT, denom, out);
}

// Round 3
// 175.669 us; speedup vs baseline: 1.9278x; 1.2171x over previous
//
#include <hip/hip_runtime.h>

#define B_   8
#define C_   256
#define W_   8192
#define F_   256
#define KK   3
#define KC   768            // KK * C_
#define WP   (W_ + 2)       // padded rows in featT (zero row at w=-1 and w=W)
#define COEF 0.03608439182435161f   // 1/sqrt(3*256)
#define BK   64             // K-elements per LDS tile row (128 B, 8 chunks of 16 B)

using f32x16 = __attribute__((ext_vector_type(16))) float;
using bf16x8 = __attribute__((ext_vector_type(8))) __bf16;

#define AS1(p) ((const __attribute__((address_space(1))) void*)(p))
#define AS3(p) ((__attribute__((address_space(3))) void*)(p))

__device__ __forceinline__ unsigned short f2bf(float x) {
    union { float f; unsigned int u; } v; v.f = x;
    unsigned int u = v.u;
    u += 0x7FFFu + ((u >> 16) & 1u);   // RNE
    return (unsigned short)(u >> 16);
}

// kT[f][k*256+c] = bf16(kernel[k][c][f] * COEF); also zeroes featT's pad rows.
__global__ void prep_kt(const float* __restrict__ kern, unsigned short* __restrict__ kT,
                        unsigned short* __restrict__ featT) {
    int idx = blockIdx.x * 256 + threadIdx.x;   // ((k*256)+c)*256 + f
    int f  = idx & 255;
    int kc = idx >> 8;
    kT[(size_t)f * KC + kc] = f2bf(kern[idx] * COEF);
    if (idx < 4096) {       // 8 b * 2 rows * 256 c pad elements
        int b = idx >> 9, r = (idx >> 8) & 1, c = idx & 255;
        size_t row = r ? (size_t)(WP - 1) : 0;
        featT[((size_t)b * WP + row) * C_ + c] = 0;
    }
}

// denom[b][f] = rsqrt( sum_{k,c} (kernel[k,c,f]*COEF*(style[b,c]+1))^2 )
// one block per b; lanes = f -> every kern load fully coalesced
__global__ __launch_bounds__(256) void prep_denom(const float* __restrict__ kern,
                                                  const float* __restrict__ style,
                                                  float* __restrict__ denom) {
    __shared__ float sst[C_];
    const int b = blockIdx.x, f = threadIdx.x;
    sst[f] = (style[b * C_ + f] + 1.0f) * COEF;
    __syncthreads();
    float sum = 0.f;
#pragma unroll 8
    for (int kc = 0; kc < KC; ++kc) {
        float w = kern[(size_t)kc * F_ + f] * sst[kc & 255];
        sum += w * w;
    }
    denom[b * F_ + f] = rsqrtf(sum);
}

// featT[b][w+1][c] = bf16( feat[b][c][w] * (style[b][c]+1) )
// 64(c) x 64(w) tile: float4 loads, modulate, LDS transpose [w][c], uint4 stores
__global__ __launch_bounds__(256) void prep_featT(const float* __restrict__ feat,
                                                  const float* __restrict__ style,
                                                  unsigned short* __restrict__ featT) {
    __shared__ float tile[64][65];   // [w][c], 65 pad -> conflict-free both phases
    const int tid = threadIdx.x;
    const int b = blockIdx.z, c0 = blockIdx.y * 64, w0 = blockIdx.x * 64;

    const int x4 = tid & 15, cl4 = tid >> 4;
#pragma unroll
    for (int p = 0; p < 4; ++p) {
        const int cl = cl4 + p * 16;
        const float s = style[b * C_ + c0 + cl] + 1.0f;
        float4 v = *(const float4*)(feat + ((size_t)b * C_ + c0 + cl) * W_ + w0 + x4 * 4);
        tile[x4 * 4 + 0][cl] = v.x * s;
        tile[x4 * 4 + 1][cl] = v.y * s;
        tile[x4 * 4 + 2][cl] = v.z * s;
        tile[x4 * 4 + 3][cl] = v.w * s;
    }
    __syncthreads();

    const int ch = tid & 7, wr = tid >> 3;   // ch: 8-c chunk, wr: 0..31
#pragma unroll
    for (int p = 0; p < 2; ++p) {
        const int w = wr + p * 32;
        unsigned int pk[4];
#pragma unroll
        for (int j = 0; j < 4; ++j) {
            float v0 = tile[w][ch * 8 + 2 * j];
            float v1 = tile[w][ch * 8 + 2 * j + 1];
            pk[j] = (unsigned int)f2bf(v0) | ((unsigned int)f2bf(v1) << 16);
        }
        uint4 u; u.x = pk[0]; u.y = pk[1]; u.z = pk[2]; u.w = pk[3];
        *(uint4*)(featT + ((size_t)b * WP + (w0 + w + 1)) * C_ + c0 + ch * 8) = u;
    }
}

// Main: 128(f) x 128(w) block tile, 4 waves each 64x64 via 2x2 of 32x32x16 MFMA.
// BK=64 -> 12 K-iters. LDS staged by global_load_lds width=16; chunk-XOR swizzle
// (applied on the GLOBAL source address) breaks ds_read_b128 bank conflicts.
__global__ __launch_bounds__(256) void conv_mod(
        const unsigned short* __restrict__ featT,
        const unsigned short* __restrict__ kT,
        const float* __restrict__ denom,
        float* __restrict__ out) {
    __shared__ unsigned short As[128 * BK];  // row r=f, 128 B/row, phys chunk p holds logical p^(r&7)
    __shared__ unsigned short Bs[128 * BK];  // row n=w

    const int tid  = threadIdx.x;
    const int b    = blockIdx.z;
    const int f0   = blockIdx.y * 128;
    const int w0   = blockIdx.x * 128;
    const int lane = tid & 63, wave = tid >> 6;
    const int wm   = (wave >> 1) * 64;   // wave f-offset
    const int wn   = (wave & 1) * 64;    // wave w-offset
    const int la   = lane & 31, kq = lane >> 5;

    // ---- staging setup: lane covers row (base + l>>3), phys chunk l&7,
    //      global source logical chunk (l&7)^(l>>3) ----
    const int lrow = lane >> 3, lchk = lane & 7, lswz = lchk ^ lrow;
    const unsigned short* asrc[4];
    const unsigned short* bsrc[4];
    int aldb[4], bldb[4];
#pragma unroll
    for (int i = 0; i < 4; ++i) {
        const int r = wave * 32 + i * 8;
        asrc[i] = kT + (size_t)(f0 + r + lrow) * KC + lswz * 8;
        bsrc[i] = featT + ((size_t)b * WP + (w0 + r + lrow)) * C_ + lswz * 8;
        aldb[i] = r * BK;
        bldb[i] = r * BK;
    }

    // ---- fragment LDS offsets (ushort indices), constant across iters ----
    int aoff[2][4], boff[2][4];
#pragma unroll
    for (int mi = 0; mi < 2; ++mi) {
        const int row = wm + mi * 32 + la;
#pragma unroll
        for (int kh = 0; kh < 4; ++kh)
            aoff[mi][kh] = row * BK + ((kh * 2 + kq) ^ (la & 7)) * 8;
    }
#pragma unroll
    for (int ni = 0; ni < 2; ++ni) {
        const int row = wn + ni * 32 + la;
#pragma unroll
        for (int kh = 0; kh < 4; ++kh)
            boff[ni][kh] = row * BK + ((kh * 2 + kq) ^ (la & 7)) * 8;
    }

    f32x16 acc[2][2] = {};

    for (int it = 0; it < 12; ++it) {
        const int kc0 = it * 64;
        __syncthreads();   // previous iter's fragment reads done
#pragma unroll
        for (int i = 0; i < 4; ++i) {
            __builtin_amdgcn_global_load_lds(AS1(asrc[i] + kc0), AS3(&As[aldb[i]]), 16, 0, 0);
            __builtin_amdgcn_global_load_lds(AS1(bsrc[i] + kc0), AS3(&Bs[bldb[i]]), 16, 0, 0);
        }
        __syncthreads();   // compiler emits vmcnt(0) drain before barrier
#pragma unroll
        for (int kh = 0; kh < 4; ++kh) {
            bf16x8 a0 = *(const bf16x8*)&As[aoff[0][kh]];
            bf16x8 a1 = *(const bf16x8*)&As[aoff[1][kh]];
            bf16x8 b0 = *(const bf16x8*)&Bs[boff[0][kh]];
            bf16x8 b1 = *(const bf16x8*)&Bs[boff[1][kh]];
            acc[0][0] = __builtin_amdgcn_mfma_f32_32x32x16_bf16(a0, b0, acc[0][0], 0, 0, 0);
            acc[0][1] = __builtin_amdgcn_mfma_f32_32x32x16_bf16(a0, b1, acc[0][1], 0, 0, 0);
            acc[1][0] = __builtin_amdgcn_mfma_f32_32x32x16_bf16(a1, b0, acc[1][0], 0, 0, 0);
            acc[1][1] = __builtin_amdgcn_mfma_f32_32x32x16_bf16(a1, b1, acc[1][1], 0, 0, 0);
        }
    }

    // ---- epilogue: C/D layout for 32x32: col=lane&31, row=(reg&3)+8*(reg>>2)+4*(lane>>5)
    //      [measured m74/m101] ----
    const int bofs = b * F_;
    float* obase = out + (size_t)0;
#pragma unroll
    for (int mi = 0; mi < 2; ++mi) {
#pragma unroll
        for (int r = 0; r < 16; ++r) {
            const int frow = (r & 3) + 8 * (r >> 2) + 4 * kq;
            const int f = f0 + wm + mi * 32 + frow;
            const float d = denom[bofs + f];
            float* orow = obase + (size_t)(bofs + f) * W_ + w0 + wn + la;
            orow[0]  = acc[mi][0][r] * d;
            orow[32] = acc[mi][1][r] * d;
        }
    }
}

extern "C" void kernel_launch(void* const* d_in, const int* in_sizes, int n_in,
                              void* d_out, int out_size, void* d_ws, size_t ws_size,
                              hipStream_t stream) {
    const float* feature = (const float*)d_in[0];   // [8,256,8192]
    const float* style   = (const float*)d_in[1];   // [8,256]
    const float* kern    = (const float*)d_in[2];   // [3,256,256]
    float* out = (float*)d_out;                     // [8,256,8192]

    // ws layout: kT (384 KiB) | denom (8 KiB) | featT (8*8194*256 bf16 = 32.0 MiB)
    unsigned short* kT    = (unsigned short*)d_ws;
    float*          denom = (float*)((char*)d_ws + (size_t)F_ * KC * 2);
    unsigned short* featT = (unsigned short*)((char*)d_ws + (size_t)F_ * KC * 2 + 8192);

    hipLaunchKernelGGL(prep_kt,    dim3(KC),     dim3(256), 0, stream, kern, kT, featT);
    hipLaunchKernelGGL(prep_denom, dim3(B_),     dim3(256), 0, stream, kern, style, denom);
    hipLaunchKernelGGL(prep_featT, dim3(W_ / 64, C_ / 64, B_), dim3(256), 0, stream,
                       feature, style, featT);
    hipLaunchKernelGGL(conv_mod,   dim3(W_ / 128, F_ / 128, B_), dim3(256), 0, stream,
                       featT, kT, denom, out);
}